// Round 2
// baseline (1346.793 us; speedup 1.0000x reference)
//
#include <hip/hip_runtime.h>
#include <cstdint>

#define VDIM 32000
#define HDIM 512
#define LDIM 128
#define BDIM 8
#define MROWS 1024
#define H2 1024
#define H3 1536
#define GRU_WGS 32
#define HSTEP 8192  // 16 rows * 512 per step (rows 8-15 zero pad)

typedef __bf16 bf16x8 __attribute__((ext_vector_type(8)));
typedef float f32x4 __attribute__((ext_vector_type(4)));

#define AS1 __attribute__((address_space(1)))
#define AS3 __attribute__((address_space(3)))

__device__ __forceinline__ unsigned short f2b(float x) {
  unsigned u = __builtin_bit_cast(unsigned, x);
  u += 0x7fffu + ((u >> 16) & 1u);
  return (unsigned short)(u >> 16);
}

__device__ __forceinline__ float wredS(float v) {
#pragma unroll
  for (int o = 32; o > 0; o >>= 1) v += __shfl_xor(v, o);
  return v;
}
__device__ __forceinline__ float wredM(float v) {
#pragma unroll
  for (int o = 32; o > 0; o >>= 1) v = fmaxf(v, __shfl_xor(v, o));
  return v;
}

__device__ __forceinline__ void gl_lds16(const void* g, void* l) {
  __builtin_amdgcn_global_load_lds((AS1 void*)const_cast<void*>(g), (AS3 void*)l, 16, 0, 0);
}

// ---------------- prep ----------------
__global__ void cvt_kernel(const float* __restrict__ src, unsigned short* __restrict__ dst, int n4) {
  int i = blockIdx.x * 256 + threadIdx.x;
  if (i < n4) {
    float4 v = ((const float4*)src)[i];
    unsigned r0 = (unsigned)f2b(v.x) | ((unsigned)f2b(v.y) << 16);
    unsigned r1 = (unsigned)f2b(v.z) | ((unsigned)f2b(v.w) << 16);
    uint2 r; r.x = r0; r.y = r1;
    *(uint2*)(dst + (size_t)i * 4) = r;
  }
}

// zero the full h ring (129 steps x 16 rows x 512) so pad rows 8-15 read 0
__global__ void hzero_kernel(unsigned short* __restrict__ hbufbf) {
  size_t i = (size_t)blockIdx.x * 256 + threadIdx.x;
  uint4 z = {0, 0, 0, 0};
  size_t n8 = (size_t)129 * HSTEP / 8;
  if (i < n8) ((uint4*)hbufbf)[i] = z;
}

__global__ void init_kernel(const float* __restrict__ h0, unsigned short* __restrict__ hbufbf,
                            float* __restrict__ rowsum, int* __restrict__ cnt) {
  int tid = threadIdx.x;
  for (int i = tid; i < BDIM * HDIM; i += 256) {
    int b = i >> 9, k = i & 511;
    hbufbf[b * 512 + k] = f2b(h0[i]);
  }
  for (int i = tid; i < MROWS; i += 256) rowsum[i] = 0.f;
  for (int i = tid; i < 160; i += 256) cnt[i] = (i == 0) ? GRU_WGS : 0;
}

__global__ void embed_kernel(const int* __restrict__ input_, const float* __restrict__ emb,
                             float* __restrict__ emb_f, unsigned short* __restrict__ A4) {
  int m = blockIdx.x, tid = threadIdx.x;
  int tok = input_[m];
  const float* src = emb + (size_t)tok * HDIM;
  for (int k = tid; k < HDIM; k += 256) {
    float v = src[k];
    emb_f[(size_t)m * HDIM + k] = v;
    A4[(size_t)m * H2 + k] = f2b(v);
  }
}

// ---------------- attention logits + softmax over axis=1 ----------------
__global__ void attn_kernel(const float* __restrict__ emb_f, const float* __restrict__ h0,
                            const float* __restrict__ attn_W, const float* __restrict__ attn_b,
                            float* __restrict__ attn_out) {
  int j = blockIdx.x, b = blockIdx.y, tid = threadIdx.x;
  int wid = tid >> 6;
  __shared__ float wj[H2];
  __shared__ float red[2];
  for (int k = tid; k < H2; k += 128) wj[k] = attn_W[(size_t)j * H2 + k];
  __syncthreads();
  float hp = 0.f;
  for (int k = tid * 4; k < tid * 4 + 4; ++k) hp += h0[b * HDIM + k] * wj[HDIM + k];
  hp = wredS(hp);
  if ((tid & 63) == 0) red[wid] = hp;
  __syncthreads();
  float hdot = red[0] + red[1];
  __syncthreads();

  int i = tid;
  const float* er = emb_f + ((size_t)(b * LDIM + i)) * HDIM;
  float acc = 0.f;
  for (int k = 0; k < HDIM; k += 4) {
    float4 e = *(const float4*)(er + k);
    acc += e.x * wj[k] + e.y * wj[k + 1] + e.z * wj[k + 2] + e.w * wj[k + 3];
  }
  float l = acc + hdot + attn_b[j];
  float mx = wredM(l);
  if ((tid & 63) == 0) red[wid] = mx;
  __syncthreads();
  mx = fmaxf(red[0], red[1]);
  __syncthreads();
  float e = __expf(l - mx);
  float s = wredS(e);
  if ((tid & 63) == 0) red[wid] = s;
  __syncthreads();
  s = red[0] + red[1];
  attn_out[(size_t)b * (LDIM * LDIM) + (size_t)i * LDIM + j] = e / s;
}

// ---------------- einsum bij,bjh->bih ----------------
__global__ void einsum_kernel(const float* __restrict__ w, const float* __restrict__ enc,
                              float* __restrict__ outF, unsigned short* __restrict__ outBf, int mode) {
  int i = blockIdx.x, b = blockIdx.y, tid = threadIdx.x;
  __shared__ float wr[LDIM];
  if (tid < LDIM) wr[tid] = w[((size_t)(b * LDIM + i)) * LDIM + tid];
  __syncthreads();
  float a0 = 0.f, a1 = 0.f;
  const float* eb = enc + (size_t)b * LDIM * HDIM;
  for (int jj = 0; jj < LDIM; ++jj) {
    float wv = wr[jj];
    const float* er = eb + (size_t)jj * HDIM;
    a0 += wv * er[tid];
    a1 += wv * er[tid + 256];
  }
  if (mode == 0) {
    size_t base = ((size_t)(b * LDIM + i)) * H2 + HDIM;
    outBf[base + tid] = f2b(a0);
    outBf[base + tid + 256] = f2b(a1);
  } else {
    size_t base = ((size_t)(b * LDIM + i)) * HDIM;
    outF[base + tid] = a0;
    outF[base + tid + 256] = a1;
  }
}

// ---------------- generic bf16 MFMA GEMM: C = A @ B^T (+bias, epilogue mode) ----------------
__global__ __launch_bounds__(256) void gemm_bt(const unsigned short* __restrict__ A,
                                               const unsigned short* __restrict__ Bw, int N, int K,
                                               const float* __restrict__ bias, int mode,
                                               float* __restrict__ outF,
                                               unsigned short* __restrict__ outBf,
                                               float* __restrict__ rowsum) {
  __shared__ unsigned short sA[4096];
  __shared__ unsigned short sB[4096];
  int tid = threadIdx.x;
  int lane = tid & 63, w = tid >> 6;
  int wm = w >> 1, wn = w & 1;
  int ln15 = lane & 15, q = lane >> 4;
  int m0 = blockIdx.y * 128, n0 = blockIdx.x * 128;
  f32x4 acc[4][4] = {};
  int rowA = tid >> 2;
  int colK = (tid & 3) * 8;
  for (int kt = 0; kt < K; kt += 32) {
    __syncthreads();
    const unsigned short* ga0 = A + (size_t)(m0 + rowA) * K + kt + colK;
    const unsigned short* ga1 = A + (size_t)(m0 + 64 + rowA) * K + kt + colK;
    const unsigned short* gb0 = Bw + (size_t)(n0 + rowA) * K + kt + colK;
    const unsigned short* gb1 = Bw + (size_t)(n0 + 64 + rowA) * K + kt + colK;
    gl_lds16(ga0, sA + w * 512);
    gl_lds16(ga1, sA + 2048 + w * 512);
    gl_lds16(gb0, sB + w * 512);
    gl_lds16(gb1, sB + 2048 + w * 512);
    __syncthreads();
    bf16x8 af[4], bf[4];
#pragma unroll
    for (int t = 0; t < 4; ++t) {
      af[t] = *(const bf16x8*)(sA + (wm * 64 + t * 16 + ln15) * 32 + q * 8);
      bf[t] = *(const bf16x8*)(sB + (wn * 64 + t * 16 + ln15) * 32 + q * 8);
    }
#pragma unroll
    for (int ti = 0; ti < 4; ++ti)
#pragma unroll
      for (int tj = 0; tj < 4; ++tj)
        acc[ti][tj] = __builtin_amdgcn_mfma_f32_16x16x32_bf16(af[ti], bf[tj], acc[ti][tj], 0, 0, 0);
  }
#pragma unroll
  for (int ti = 0; ti < 4; ++ti) {
#pragma unroll
    for (int reg = 0; reg < 4; ++reg) {
      int m = m0 + wm * 64 + ti * 16 + q * 4 + reg;
      float s = 0.f;
#pragma unroll
      for (int tj = 0; tj < 4; ++tj) {
        int n = n0 + wn * 64 + tj * 16 + ln15;
        float c = acc[ti][tj][reg] + bias[n];
        if (mode == 2) {
          float e = __expf(c);
          outF[(size_t)m * N + n] = e;
          s += e;
        } else if (mode == 0) {
          outBf[(size_t)m * N + n] = f2b(fmaxf(c, 0.f));
        } else {
          outF[(size_t)m * N + n] = c;
        }
      }
      if (mode == 2) {
        s += __shfl_xor(s, 1); s += __shfl_xor(s, 2);
        s += __shfl_xor(s, 4); s += __shfl_xor(s, 8);
        if (ln15 == 0) atomicAdd(&rowsum[m], s);
      }
    }
  }
}

// ---------------- sequential GRU: 32 persistent single-wave WGs ----------------
// sW fragment-ordered: sW[((gate*16+kk)*64 + lane)*8 + e] =
//   bf16(Whh[(gate*512 + g*16 + (lane&15))*512 + kk*32 + (lane>>4)*8 + e])
// -> ds_read_b128 with consecutive lanes 16B apart: conflict-free.
__global__ __launch_bounds__(64) void gru_kernel(const float* __restrict__ Whh,
                                                 const float* __restrict__ bhh,
                                                 const float* __restrict__ gi,
                                                 const float* __restrict__ h0,
                                                 unsigned short* __restrict__ hbufbf,
                                                 float* __restrict__ outF,
                                                 unsigned short* __restrict__ Ab,
                                                 int* __restrict__ cnt) {
  __shared__ unsigned short sW[3 * 16 * 64 * 8];  // 48 KB
  int g = blockIdx.x, lane = threadIdx.x;
  int ln15 = lane & 15, q = lane >> 4;
  int j = g * 16 + ln15;
#pragma unroll 1
  for (int gate = 0; gate < 3; ++gate) {
#pragma unroll 1
    for (int kk = 0; kk < 16; ++kk) {
      const float* src = Whh + (size_t)(gate * 512 + g * 16 + ln15) * 512 + kk * 32 + q * 8;
      float4 v0 = *(const float4*)src, v1 = *(const float4*)(src + 4);
      unsigned short* dst = sW + (size_t)((gate * 16 + kk) * 64 + lane) * 8;
      dst[0] = f2b(v0.x); dst[1] = f2b(v0.y); dst[2] = f2b(v0.z); dst[3] = f2b(v0.w);
      dst[4] = f2b(v1.x); dst[5] = f2b(v1.y); dst[6] = f2b(v1.z); dst[7] = f2b(v1.w);
    }
  }
  float bh_r = bhh[j], bh_z = bhh[512 + j], bh_n = bhh[1024 + j];
  float hreg[4];
  if (q < 2) {
#pragma unroll
    for (int reg = 0; reg < 4; ++reg) hreg[reg] = h0[(q * 4 + reg) * 512 + j];
  }
  __syncthreads();

  for (int t = 0; t < 128; ++t) {
    // prefetch gi for this step BEFORE the barrier (independent of h)
    float gir[4], giz[4], gin[4];
    if (q < 2) {
#pragma unroll
      for (int reg = 0; reg < 4; ++reg) {
        size_t gib = ((size_t)((q * 4 + reg) * 128 + t)) * H3;
        gir[reg] = gi[gib + j];
        giz[reg] = gi[gib + 512 + j];
        gin[reg] = gi[gib + 1024 + j];
      }
    }
    if (lane == 0) {
      while (__hip_atomic_load(&cnt[t], __ATOMIC_ACQUIRE, __HIP_MEMORY_SCOPE_AGENT) < GRU_WGS)
        __builtin_amdgcn_s_sleep(1);
    }
    __syncthreads();
    // A-fragments straight from global (row = ln15; rows 8-15 are the zero pad)
    const unsigned short* hT = hbufbf + (size_t)t * HSTEP + ln15 * 512 + q * 8;
    bf16x8 aF[16];
#pragma unroll
    for (int kk = 0; kk < 16; ++kk) aF[kk] = *(const bf16x8*)(hT + kk * 32);
    f32x4 ac0 = {}, ac1 = {}, ac2 = {};
#pragma unroll
    for (int kk = 0; kk < 16; ++kk) {
      bf16x8 b0 = *(const bf16x8*)(sW + (size_t)((0 * 16 + kk) * 64 + lane) * 8);
      bf16x8 b1 = *(const bf16x8*)(sW + (size_t)((1 * 16 + kk) * 64 + lane) * 8);
      bf16x8 b2 = *(const bf16x8*)(sW + (size_t)((2 * 16 + kk) * 64 + lane) * 8);
      ac0 = __builtin_amdgcn_mfma_f32_16x16x32_bf16(aF[kk], b0, ac0, 0, 0, 0);
      ac1 = __builtin_amdgcn_mfma_f32_16x16x32_bf16(aF[kk], b1, ac1, 0, 0, 0);
      ac2 = __builtin_amdgcn_mfma_f32_16x16x32_bf16(aF[kk], b2, ac2, 0, 0, 0);
    }
    float hv[4];
    if (q < 2) {
#pragma unroll
      for (int reg = 0; reg < 4; ++reg) {
        int b = q * 4 + reg;
        float rr = 1.f / (1.f + __expf(-(gir[reg] + ac0[reg] + bh_r)));
        float zz = 1.f / (1.f + __expf(-(giz[reg] + ac1[reg] + bh_z)));
        float narg = gin[reg] + rr * (ac2[reg] + bh_n);
        narg = fminf(fmaxf(narg, -20.f), 20.f);
        float te = __expf(2.f * narg);
        float nn = (te - 1.f) / (te + 1.f);
        hv[reg] = (1.f - zz) * nn + zz * hreg[reg];
        hreg[reg] = hv[reg];
        // only the h ring store must precede the release
        hbufbf[(size_t)(t + 1) * HSTEP + b * 512 + j] = f2b(hv[reg]);
      }
    }
    if (lane == 0)
      __hip_atomic_fetch_add(&cnt[t + 1], 1, __ATOMIC_RELEASE, __HIP_MEMORY_SCOPE_AGENT);
    // off the critical path: consumed only after kernel end
    if (q < 2) {
#pragma unroll
      for (int reg = 0; reg < 4; ++reg) {
        int b = q * 4 + reg;
        size_t orow = ((size_t)b * 128 + t) * 512 + j;
        outF[orow] = hv[reg];
        Ab[orow] = f2b(hv[reg]);
      }
    }
  }
}

// ---------------- copy-attention small kernels ----------------
__global__ void dots_kernel(const float* __restrict__ enc, const float* __restrict__ outF,
                            const float* __restrict__ copyW, float* __restrict__ epart,
                            float* __restrict__ dpart) {
  int tid = threadIdx.x, lane = tid & 63, wid = tid >> 6;
  int gw = blockIdx.x * 4 + wid;
  for (int row = gw; row < 2048; row += 128) {
    const float* src;
    const float* wv;
    float* dst;
    int r;
    if (row < 1024) { src = enc + (size_t)row * 512; wv = copyW; dst = epart; r = row; }
    else { src = outF + (size_t)(row - 1024) * 512; wv = copyW + 512; dst = dpart; r = row - 1024; }
    float4 s1 = *(const float4*)(src + lane * 8);
    float4 s2 = *(const float4*)(src + lane * 8 + 4);
    float4 w1 = *(const float4*)(wv + lane * 8);
    float4 w2 = *(const float4*)(wv + lane * 8 + 4);
    float p = s1.x * w1.x + s1.y * w1.y + s1.z * w1.z + s1.w * w1.w +
              s2.x * w2.x + s2.y * w2.y + s2.z * w2.z + s2.w * w2.w;
    p = wredS(p);
    if (lane == 0) dst[r] = p;
  }
}

__global__ void alphas_kernel(const float* __restrict__ dpart, const float* __restrict__ epart,
                              const int* __restrict__ enc_in, const float* __restrict__ copy_b,
                              float* __restrict__ alphas) {
  int i = blockIdx.x, b = blockIdx.y, jt = threadIdx.x;
  int wid = jt >> 6;
  __shared__ float red[2];
  float l = dpart[b * 128 + i] + epart[b * 128 + jt] + copy_b[0] +
            (enc_in[b * 128 + jt] == 0 ? -1000.f : 0.f);
  float mx = wredM(l);
  if ((jt & 63) == 0) red[wid] = mx;
  __syncthreads();
  mx = fmaxf(red[0], red[1]);
  __syncthreads();
  float e = __expf(l - mx);
  float s = wredS(e);
  if ((jt & 63) == 0) red[wid] = s;
  __syncthreads();
  s = red[0] + red[1];
  alphas[((size_t)(b * 128 + i)) * 128 + jt] = e / s;
}

__global__ void mix_kernel(const float* __restrict__ outF, const float* __restrict__ ctx,
                           const float* __restrict__ emb_f, const float* __restrict__ dogenW,
                           const float* __restrict__ dogenB, float* __restrict__ mixb) {
  int tid = threadIdx.x, lane = tid & 63, wid = tid >> 6;
  int gw = blockIdx.x * 4 + wid;
  for (int row = gw; row < 1024; row += 64) {
    int k = lane * 8;
    const float* o = outF + (size_t)row * 512;
    const float* c = ctx + (size_t)row * 512;
    const float* e = emb_f + (size_t)row * 512;
    float p = 0.f;
#pragma unroll
    for (int u = 0; u < 8; ++u)
      p += o[k + u] * dogenW[k + u] + c[k + u] * dogenW[512 + k + u] + e[k + u] * dogenW[1024 + k + u];
    p = wredS(p);
    if (lane == 0) mixb[row] = 1.f / (1.f + __expf(-(p + dogenB[0])));
  }
}

__global__ void final_kernel(float* __restrict__ prob, const float* __restrict__ mixb,
                             const float* __restrict__ rowsum, const int* __restrict__ enc_in) {
  int row = blockIdx.y;
  int v = blockIdx.x * 256 + threadIdx.x;
  float mx = mixb[row], rs = rowsum[row];
  size_t idx = (size_t)row * VDIM + v;
  float val = prob[idx] * (mx / rs);
  if (v == enc_in[row]) val += 1.f - mx;
  prob[idx] = val;
}

// ---------------- host ----------------
extern "C" void kernel_launch(void* const* d_in, const int* in_sizes, int n_in, void* d_out,
                              int out_size, void* d_ws, size_t ws_size, hipStream_t stream) {
  const int* input_ = (const int*)d_in[0];
  const int* enc_in = (const int*)d_in[1];
  const float* enc_h = (const float*)d_in[2];
  const float* enc_out = (const float*)d_in[3];
  const float* emb = (const float*)d_in[4];
  const float* attn_W = (const float*)d_in[5];
  const float* attn_b = (const float*)d_in[6];
  const float* comb_W = (const float*)d_in[7];
  const float* comb_b = (const float*)d_in[8];
  const float* Wih = (const float*)d_in[9];
  const float* Whh = (const float*)d_in[10];
  const float* bih = (const float*)d_in[11];
  const float* bhh = (const float*)d_in[12];
  const float* out_W = (const float*)d_in[13];
  const float* out_b = (const float*)d_in[14];
  const float* dogen_W = (const float*)d_in[15];
  const float* dogen_b = (const float*)d_in[16];
  const float* copy_W = (const float*)d_in[17];
  const float* copy_b = (const float*)d_in[18];

  float* prob = (float*)d_out;
  float* attn_out = prob + (size_t)MROWS * VDIM;

  char* ws = (char*)d_ws;
  size_t off = 0;
  auto alloc = [&](size_t bytes) {
    off = (off + 255) & ~(size_t)255;
    void* p = ws + off;
    off += bytes;
    return p;
  };
  unsigned short* outW_bf = (unsigned short*)alloc((size_t)VDIM * HDIM * 2);
  unsigned short* combW_bf = (unsigned short*)alloc((size_t)HDIM * H2 * 2);
  unsigned short* Wih_bf = (unsigned short*)alloc((size_t)H3 * HDIM * 2);
  unsigned short* A4 = (unsigned short*)alloc((size_t)MROWS * H2 * 2);
  unsigned short* xbf = (unsigned short*)alloc((size_t)MROWS * HDIM * 2);
  unsigned short* Ab = (unsigned short*)alloc((size_t)MROWS * HDIM * 2);
  float* emb_f = (float*)alloc((size_t)MROWS * HDIM * 4);
  float* gi = (float*)alloc((size_t)MROWS * H3 * 4);
  float* outF = (float*)alloc((size_t)MROWS * HDIM * 4);
  unsigned short* hbufbf = (unsigned short*)alloc((size_t)129 * HSTEP * 2);
  int* cnt = (int*)alloc(1024);
  float* rowsum = (float*)alloc(4096);
  float* epart = (float*)alloc(4096);
  float* dpart = (float*)alloc(4096);
  float* alphas = (float*)alloc((size_t)MROWS * LDIM * 4);
  float* ctx = (float*)alloc((size_t)MROWS * HDIM * 4);
  float* mixb = (float*)alloc(4096);

  // prep: converts + init
  cvt_kernel<<<(VDIM * HDIM / 4 + 255) / 256, 256, 0, stream>>>(out_W, outW_bf, VDIM * HDIM / 4);
  cvt_kernel<<<(HDIM * H2 / 4 + 255) / 256, 256, 0, stream>>>(comb_W, combW_bf, HDIM * H2 / 4);
  cvt_kernel<<<(H3 * HDIM / 4 + 255) / 256, 256, 0, stream>>>(Wih, Wih_bf, H3 * HDIM / 4);
  {
    int n8 = (int)((size_t)129 * HSTEP / 8);
    hzero_kernel<<<(n8 + 255) / 256, 256, 0, stream>>>(hbufbf);
  }
  init_kernel<<<1, 256, 0, stream>>>(enc_h, hbufbf, rowsum, cnt);
  embed_kernel<<<MROWS, 256, 0, stream>>>(input_, emb, emb_f, A4);
  // attention path (fp32)
  attn_kernel<<<dim3(LDIM, BDIM), 128, 0, stream>>>(emb_f, enc_h, attn_W, attn_b, attn_out);
  einsum_kernel<<<dim3(LDIM, BDIM), 256, 0, stream>>>(attn_out, enc_out, nullptr, A4, 0);
  // comb GEMM -> x (bf16), gi GEMM
  gemm_bt<<<dim3(4, 8), 256, 0, stream>>>(A4, combW_bf, HDIM, H2, comb_b, 0, nullptr, xbf, nullptr);
  gemm_bt<<<dim3(12, 8), 256, 0, stream>>>(xbf, Wih_bf, H3, HDIM, bih, 1, gi, nullptr, nullptr);
  // sequential GRU
  gru_kernel<<<GRU_WGS, 64, 0, stream>>>(Whh, bhh, gi, enc_h, hbufbf, outF, Ab, cnt);
  // big output GEMM: explogits into prob region + row sums
  gemm_bt<<<dim3(VDIM / 128, 8), 256, 0, stream>>>(Ab, outW_bf, VDIM, HDIM, out_b, 2, prob, nullptr, rowsum);
  // copy path
  dots_kernel<<<32, 256, 0, stream>>>(enc_out, outF, copy_W, epart, dpart);
  alphas_kernel<<<dim3(LDIM, BDIM), 128, 0, stream>>>(dpart, epart, enc_in, copy_b, alphas);
  einsum_kernel<<<dim3(LDIM, BDIM), 256, 0, stream>>>(alphas, enc_out, ctx, nullptr, 1);
  mix_kernel<<<16, 256, 0, stream>>>(outF, ctx, emb_f, dogen_W, dogen_b, mixb);
  // final blend (in-place on prob region)
  final_kernel<<<dim3(VDIM / 256, MROWS), 256, 0, stream>>>(prob, mixb, rowsum, enc_in);
}

// Round 3
// 1112.436 us; speedup vs baseline: 1.2107x; 1.2107x over previous
//
#include <hip/hip_runtime.h>
#include <cstdint>

#define VDIM 32000
#define HDIM 512
#define LDIM 128
#define BDIM 8
#define MROWS 1024
#define H2 1024
#define H3 1536
#define GRU_WGS 32
#define HSTEP 4096  // 8 rows * 512 per step

typedef __bf16 bf16x8 __attribute__((ext_vector_type(8)));
typedef float f32x4 __attribute__((ext_vector_type(4)));

#define AS1 __attribute__((address_space(1)))
#define AS3 __attribute__((address_space(3)))

__device__ __forceinline__ unsigned short f2b(float x) {
  unsigned u = __builtin_bit_cast(unsigned, x);
  u += 0x7fffu + ((u >> 16) & 1u);
  return (unsigned short)(u >> 16);
}

__device__ __forceinline__ float wredS(float v) {
#pragma unroll
  for (int o = 32; o > 0; o >>= 1) v += __shfl_xor(v, o);
  return v;
}
__device__ __forceinline__ float wredM(float v) {
#pragma unroll
  for (int o = 32; o > 0; o >>= 1) v = fmaxf(v, __shfl_xor(v, o));
  return v;
}

__device__ __forceinline__ void gl_lds16(const void* g, void* l) {
  __builtin_amdgcn_global_load_lds((AS1 void*)const_cast<void*>(g), (AS3 void*)l, 16, 0, 0);
}

// ---------------- prep ----------------
__global__ void cvt_kernel(const float* __restrict__ src, unsigned short* __restrict__ dst, int n4) {
  int i = blockIdx.x * 256 + threadIdx.x;
  if (i < n4) {
    float4 v = ((const float4*)src)[i];
    unsigned r0 = (unsigned)f2b(v.x) | ((unsigned)f2b(v.y) << 16);
    unsigned r1 = (unsigned)f2b(v.z) | ((unsigned)f2b(v.w) << 16);
    uint2 r; r.x = r0; r.y = r1;
    *(uint2*)(dst + (size_t)i * 4) = r;
  }
}

__global__ void init_kernel(const float* __restrict__ h0, unsigned short* __restrict__ hbufbf,
                            float* __restrict__ rowsum, int* __restrict__ flags) {
  int tid = threadIdx.x;
  for (int i = tid; i < BDIM * HDIM; i += 256) {
    int b = i >> 9, k = i & 511;
    hbufbf[b * 512 + k] = f2b(h0[i]);
  }
  for (int i = tid; i < MROWS; i += 256) rowsum[i] = 0.f;
  for (int i = tid; i < 129 * GRU_WGS; i += 256) flags[i] = (i < GRU_WGS) ? 1 : 0;
}

__global__ void embed_kernel(const int* __restrict__ input_, const float* __restrict__ emb,
                             float* __restrict__ emb_f, unsigned short* __restrict__ A4) {
  int m = blockIdx.x, tid = threadIdx.x;
  int tok = input_[m];
  const float* src = emb + (size_t)tok * HDIM;
  for (int k = tid; k < HDIM; k += 256) {
    float v = src[k];
    emb_f[(size_t)m * HDIM + k] = v;
    A4[(size_t)m * H2 + k] = f2b(v);
  }
}

// ---------------- attention logits + softmax over axis=1 ----------------
__global__ void attn_kernel(const float* __restrict__ emb_f, const float* __restrict__ h0,
                            const float* __restrict__ attn_W, const float* __restrict__ attn_b,
                            float* __restrict__ attn_out) {
  int j = blockIdx.x, b = blockIdx.y, tid = threadIdx.x;
  int wid = tid >> 6;
  __shared__ float wj[H2];
  __shared__ float red[2];
  for (int k = tid; k < H2; k += 128) wj[k] = attn_W[(size_t)j * H2 + k];
  __syncthreads();
  float hp = 0.f;
  for (int k = tid * 4; k < tid * 4 + 4; ++k) hp += h0[b * HDIM + k] * wj[HDIM + k];
  hp = wredS(hp);
  if ((tid & 63) == 0) red[wid] = hp;
  __syncthreads();
  float hdot = red[0] + red[1];
  __syncthreads();

  int i = tid;
  const float* er = emb_f + ((size_t)(b * LDIM + i)) * HDIM;
  float acc = 0.f;
  for (int k = 0; k < HDIM; k += 4) {
    float4 e = *(const float4*)(er + k);
    acc += e.x * wj[k] + e.y * wj[k + 1] + e.z * wj[k + 2] + e.w * wj[k + 3];
  }
  float l = acc + hdot + attn_b[j];
  float mx = wredM(l);
  if ((tid & 63) == 0) red[wid] = mx;
  __syncthreads();
  mx = fmaxf(red[0], red[1]);
  __syncthreads();
  float e = __expf(l - mx);
  float s = wredS(e);
  if ((tid & 63) == 0) red[wid] = s;
  __syncthreads();
  s = red[0] + red[1];
  attn_out[(size_t)b * (LDIM * LDIM) + (size_t)i * LDIM + j] = e / s;
}

// ---------------- einsum bij,bjh->bih ----------------
__global__ void einsum_kernel(const float* __restrict__ w, const float* __restrict__ enc,
                              float* __restrict__ outF, unsigned short* __restrict__ outBf, int mode) {
  int i = blockIdx.x, b = blockIdx.y, tid = threadIdx.x;
  __shared__ float wr[LDIM];
  if (tid < LDIM) wr[tid] = w[((size_t)(b * LDIM + i)) * LDIM + tid];
  __syncthreads();
  float a0 = 0.f, a1 = 0.f;
  const float* eb = enc + (size_t)b * LDIM * HDIM;
  for (int jj = 0; jj < LDIM; ++jj) {
    float wv = wr[jj];
    const float* er = eb + (size_t)jj * HDIM;
    a0 += wv * er[tid];
    a1 += wv * er[tid + 256];
  }
  if (mode == 0) {
    size_t base = ((size_t)(b * LDIM + i)) * H2 + HDIM;
    outBf[base + tid] = f2b(a0);
    outBf[base + tid + 256] = f2b(a1);
  } else {
    size_t base = ((size_t)(b * LDIM + i)) * HDIM;
    outF[base + tid] = a0;
    outF[base + tid + 256] = a1;
  }
}

// ---------------- generic bf16 MFMA GEMM: C = A @ B^T (+bias, epilogue mode) ----------------
__global__ __launch_bounds__(256) void gemm_bt(const unsigned short* __restrict__ A,
                                               const unsigned short* __restrict__ Bw, int N, int K,
                                               const float* __restrict__ bias, int mode,
                                               float* __restrict__ outF,
                                               unsigned short* __restrict__ outBf,
                                               float* __restrict__ rowsum) {
  __shared__ unsigned short sA[4096];
  __shared__ unsigned short sB[4096];
  int tid = threadIdx.x;
  int lane = tid & 63, w = tid >> 6;
  int wm = w >> 1, wn = w & 1;
  int ln15 = lane & 15, q = lane >> 4;
  int m0 = blockIdx.y * 128, n0 = blockIdx.x * 128;
  f32x4 acc[4][4] = {};
  int rowA = tid >> 2;
  int colK = (tid & 3) * 8;
  for (int kt = 0; kt < K; kt += 32) {
    __syncthreads();
    const unsigned short* ga0 = A + (size_t)(m0 + rowA) * K + kt + colK;
    const unsigned short* ga1 = A + (size_t)(m0 + 64 + rowA) * K + kt + colK;
    const unsigned short* gb0 = Bw + (size_t)(n0 + rowA) * K + kt + colK;
    const unsigned short* gb1 = Bw + (size_t)(n0 + 64 + rowA) * K + kt + colK;
    gl_lds16(ga0, sA + w * 512);
    gl_lds16(ga1, sA + 2048 + w * 512);
    gl_lds16(gb0, sB + w * 512);
    gl_lds16(gb1, sB + 2048 + w * 512);
    __syncthreads();
    bf16x8 af[4], bf[4];
#pragma unroll
    for (int t = 0; t < 4; ++t) {
      af[t] = *(const bf16x8*)(sA + (wm * 64 + t * 16 + ln15) * 32 + q * 8);
      bf[t] = *(const bf16x8*)(sB + (wn * 64 + t * 16 + ln15) * 32 + q * 8);
    }
#pragma unroll
    for (int ti = 0; ti < 4; ++ti)
#pragma unroll
      for (int tj = 0; tj < 4; ++tj)
        acc[ti][tj] = __builtin_amdgcn_mfma_f32_16x16x32_bf16(af[ti], bf[tj], acc[ti][tj], 0, 0, 0);
  }
#pragma unroll
  for (int ti = 0; ti < 4; ++ti) {
#pragma unroll
    for (int reg = 0; reg < 4; ++reg) {
      int m = m0 + wm * 64 + ti * 16 + q * 4 + reg;
      float s = 0.f;
#pragma unroll
      for (int tj = 0; tj < 4; ++tj) {
        int n = n0 + wn * 64 + tj * 16 + ln15;
        float c = acc[ti][tj][reg] + bias[n];
        if (mode == 2) {
          float e = __expf(c);
          outF[(size_t)m * N + n] = e;
          s += e;
        } else if (mode == 0) {
          outBf[(size_t)m * N + n] = f2b(fmaxf(c, 0.f));
        } else {
          outF[(size_t)m * N + n] = c;
        }
      }
      if (mode == 2) {
        s += __shfl_xor(s, 1); s += __shfl_xor(s, 2);
        s += __shfl_xor(s, 4); s += __shfl_xor(s, 8);
        if (ln15 == 0) atomicAdd(&rowsum[m], s);
      }
    }
  }
}

// ---------------- sequential GRU: 32 persistent single-wave WGs ----------------
// Barrier v3: per-WG flag stores (write-through sc0sc1, no atomic RMW), relaxed
// IC polls (no buffer_inv per poll), one acquire fence after detect. All loop
// stores are write-through so the release fence's wbl2 finds no dirty L2.
__global__ __launch_bounds__(64) void gru_kernel(const float* __restrict__ Whh,
                                                 const float* __restrict__ bhh,
                                                 const float* __restrict__ gi,
                                                 const float* __restrict__ h0,
                                                 unsigned short* __restrict__ hbufbf,
                                                 float* __restrict__ outF,
                                                 unsigned short* __restrict__ Ab,
                                                 int* __restrict__ flags) {
  __shared__ unsigned short sW[3 * 16 * 64 * 8];  // 48 KB, fragment-ordered
  int g = blockIdx.x, lane = threadIdx.x;
  int ln15 = lane & 15, q = lane >> 4;
  int j = g * 16 + ln15;
#pragma unroll 1
  for (int gate = 0; gate < 3; ++gate) {
#pragma unroll 1
    for (int kk = 0; kk < 16; ++kk) {
      const float* src = Whh + (size_t)(gate * 512 + g * 16 + ln15) * 512 + kk * 32 + q * 8;
      float4 v0 = *(const float4*)src, v1 = *(const float4*)(src + 4);
      unsigned short* dst = sW + (size_t)((gate * 16 + kk) * 64 + lane) * 8;
      dst[0] = f2b(v0.x); dst[1] = f2b(v0.y); dst[2] = f2b(v0.z); dst[3] = f2b(v0.w);
      dst[4] = f2b(v1.x); dst[5] = f2b(v1.y); dst[6] = f2b(v1.z); dst[7] = f2b(v1.w);
    }
  }
  float bh_r = bhh[j], bh_z = bhh[512 + j], bh_n = bhh[1024 + j];
  float hreg[4] = {0.f, 0.f, 0.f, 0.f};
  if (q < 2) {
#pragma unroll
    for (int reg = 0; reg < 4; ++reg) hreg[reg] = h0[(q * 4 + reg) * 512 + j];
  }
  __syncthreads();

  for (int t = 0; t < 128; ++t) {
    // prefetch gi for this step BEFORE the barrier (independent of h)
    float gir[4], giz[4], gin[4];
    if (q < 2) {
#pragma unroll
      for (int reg = 0; reg < 4; ++reg) {
        size_t gib = ((size_t)((q * 4 + reg) * 128 + t)) * H3;
        gir[reg] = gi[gib + j];
        giz[reg] = gi[gib + 512 + j];
        gin[reg] = gi[gib + 1024 + j];
      }
    }
    // spin: relaxed IC polls, ballot-combined across 64 lanes (2 flags/lane view)
    const int* fl = flags + t * GRU_WGS;
    for (int spin = 0; spin < (1 << 20); ++spin) {
      int f = __hip_atomic_load(&fl[lane & 31], __ATOMIC_RELAXED, __HIP_MEMORY_SCOPE_AGENT);
      if (__ballot(f != 0) == ~0ull) break;
      __builtin_amdgcn_s_sleep(1);
    }
    __builtin_amdgcn_fence(__ATOMIC_ACQUIRE, "agent");
    // A-fragments straight from global; rows 8-15 are structurally zero
    bf16x8 aF[16] = {};
    if (ln15 < 8) {
      const unsigned short* hT = hbufbf + (size_t)t * HSTEP + ln15 * 512 + q * 8;
#pragma unroll
      for (int kk = 0; kk < 16; ++kk) aF[kk] = *(const bf16x8*)(hT + kk * 32);
    }
    // MFMA: split each accumulate chain 16 -> 2x8 for latency
    f32x4 c0a = {}, c0b = {}, c1a = {}, c1b = {}, c2a = {}, c2b = {};
#pragma unroll
    for (int kk = 0; kk < 8; ++kk) {
      bf16x8 b0 = *(const bf16x8*)(sW + (size_t)((0 * 16 + kk) * 64 + lane) * 8);
      bf16x8 b1 = *(const bf16x8*)(sW + (size_t)((1 * 16 + kk) * 64 + lane) * 8);
      bf16x8 b2 = *(const bf16x8*)(sW + (size_t)((2 * 16 + kk) * 64 + lane) * 8);
      c0a = __builtin_amdgcn_mfma_f32_16x16x32_bf16(aF[kk], b0, c0a, 0, 0, 0);
      c1a = __builtin_amdgcn_mfma_f32_16x16x32_bf16(aF[kk], b1, c1a, 0, 0, 0);
      c2a = __builtin_amdgcn_mfma_f32_16x16x32_bf16(aF[kk], b2, c2a, 0, 0, 0);
    }
#pragma unroll
    for (int kk = 8; kk < 16; ++kk) {
      bf16x8 b0 = *(const bf16x8*)(sW + (size_t)((0 * 16 + kk) * 64 + lane) * 8);
      bf16x8 b1 = *(const bf16x8*)(sW + (size_t)((1 * 16 + kk) * 64 + lane) * 8);
      bf16x8 b2 = *(const bf16x8*)(sW + (size_t)((2 * 16 + kk) * 64 + lane) * 8);
      c0b = __builtin_amdgcn_mfma_f32_16x16x32_bf16(aF[kk], b0, c0b, 0, 0, 0);
      c1b = __builtin_amdgcn_mfma_f32_16x16x32_bf16(aF[kk], b1, c1b, 0, 0, 0);
      c2b = __builtin_amdgcn_mfma_f32_16x16x32_bf16(aF[kk], b2, c2b, 0, 0, 0);
    }
    f32x4 ac0 = c0a + c0b, ac1 = c1a + c1b, ac2 = c2a + c2b;

    float hv[4] = {0.f, 0.f, 0.f, 0.f};
    if (q < 2) {
#pragma unroll
      for (int reg = 0; reg < 4; ++reg) {
        float rr = 1.f / (1.f + __expf(-(gir[reg] + ac0[reg] + bh_r)));
        float zz = 1.f / (1.f + __expf(-(giz[reg] + ac1[reg] + bh_z)));
        float narg = gin[reg] + rr * (ac2[reg] + bh_n);
        narg = fminf(fmaxf(narg, -20.f), 20.f);
        float te = __expf(2.f * narg);
        float nn = (te - 1.f) / (te + 1.f);
        hv[reg] = (1.f - zz) * nn + zz * hreg[reg];
        hreg[reg] = hv[reg];
      }
    }
    // pack pairs (even lane = low j) and write-through h ring (sc0 sc1)
    unsigned hb[4];
    unsigned long long ofp[4];
#pragma unroll
    for (int reg = 0; reg < 4; ++reg) {
      unsigned v = (unsigned)f2b(hv[reg]);
      unsigned pv = (unsigned)__shfl_xor((int)v, 1);
      hb[reg] = v | (pv << 16);
      unsigned fo = __builtin_bit_cast(unsigned, hv[reg]);
      unsigned fp = (unsigned)__shfl_xor((int)fo, 1);
      ofp[reg] = (unsigned long long)fo | ((unsigned long long)fp << 32);
    }
    bool st = (q < 2) && ((lane & 1) == 0);
    if (st) {
      unsigned* hrow = (unsigned*)hbufbf;
#pragma unroll
      for (int reg = 0; reg < 4; ++reg) {
        int b = q * 4 + reg;
        __hip_atomic_store(&hrow[(size_t)(t + 1) * (HSTEP / 2) + b * 256 + (j >> 1)], hb[reg],
                           __ATOMIC_RELAXED, __HIP_MEMORY_SCOPE_AGENT);
      }
    }
    __builtin_amdgcn_fence(__ATOMIC_RELEASE, "agent");
    if (lane == 0)
      __hip_atomic_store(&flags[(t + 1) * GRU_WGS + g], 1, __ATOMIC_RELAXED,
                         __HIP_MEMORY_SCOPE_AGENT);
    // off the critical path: outF/Ab (write-through so L2 stays clean)
    if (st) {
      unsigned* abrow = (unsigned*)Ab;
      unsigned long long* ofrow = (unsigned long long*)outF;
#pragma unroll
      for (int reg = 0; reg < 4; ++reg) {
        int b = q * 4 + reg;
        size_t orow2 = ((size_t)b * 128 + t) * 256 + (j >> 1);
        __hip_atomic_store(&abrow[orow2], hb[reg], __ATOMIC_RELAXED, __HIP_MEMORY_SCOPE_AGENT);
        __hip_atomic_store(&ofrow[orow2], ofp[reg], __ATOMIC_RELAXED, __HIP_MEMORY_SCOPE_AGENT);
      }
    }
  }
}

// ---------------- copy-attention small kernels ----------------
__global__ void dots_kernel(const float* __restrict__ enc, const float* __restrict__ outF,
                            const float* __restrict__ copyW, float* __restrict__ epart,
                            float* __restrict__ dpart) {
  int tid = threadIdx.x, lane = tid & 63, wid = tid >> 6;
  int gw = blockIdx.x * 4 + wid;
  for (int row = gw; row < 2048; row += 128) {
    const float* src;
    const float* wv;
    float* dst;
    int r;
    if (row < 1024) { src = enc + (size_t)row * 512; wv = copyW; dst = epart; r = row; }
    else { src = outF + (size_t)(row - 1024) * 512; wv = copyW + 512; dst = dpart; r = row - 1024; }
    float4 s1 = *(const float4*)(src + lane * 8);
    float4 s2 = *(const float4*)(src + lane * 8 + 4);
    float4 w1 = *(const float4*)(wv + lane * 8);
    float4 w2 = *(const float4*)(wv + lane * 8 + 4);
    float p = s1.x * w1.x + s1.y * w1.y + s1.z * w1.z + s1.w * w1.w +
              s2.x * w2.x + s2.y * w2.y + s2.z * w2.z + s2.w * w2.w;
    p = wredS(p);
    if (lane == 0) dst[r] = p;
  }
}

__global__ void alphas_kernel(const float* __restrict__ dpart, const float* __restrict__ epart,
                              const int* __restrict__ enc_in, const float* __restrict__ copy_b,
                              float* __restrict__ alphas) {
  int i = blockIdx.x, b = blockIdx.y, jt = threadIdx.x;
  int wid = jt >> 6;
  __shared__ float red[2];
  float l = dpart[b * 128 + i] + epart[b * 128 + jt] + copy_b[0] +
            (enc_in[b * 128 + jt] == 0 ? -1000.f : 0.f);
  float mx = wredM(l);
  if ((jt & 63) == 0) red[wid] = mx;
  __syncthreads();
  mx = fmaxf(red[0], red[1]);
  __syncthreads();
  float e = __expf(l - mx);
  float s = wredS(e);
  if ((jt & 63) == 0) red[wid] = s;
  __syncthreads();
  s = red[0] + red[1];
  alphas[((size_t)(b * 128 + i)) * 128 + jt] = e / s;
}

__global__ void mix_kernel(const float* __restrict__ outF, const float* __restrict__ ctx,
                           const float* __restrict__ emb_f, const float* __restrict__ dogenW,
                           const float* __restrict__ dogenB, float* __restrict__ mixb) {
  int tid = threadIdx.x, lane = tid & 63, wid = tid >> 6;
  int gw = blockIdx.x * 4 + wid;
  for (int row = gw; row < 1024; row += 64) {
    int k = lane * 8;
    const float* o = outF + (size_t)row * 512;
    const float* c = ctx + (size_t)row * 512;
    const float* e = emb_f + (size_t)row * 512;
    float p = 0.f;
#pragma unroll
    for (int u = 0; u < 8; ++u)
      p += o[k + u] * dogenW[k + u] + c[k + u] * dogenW[512 + k + u] + e[k + u] * dogenW[1024 + k + u];
    p = wredS(p);
    if (lane == 0) mixb[row] = 1.f / (1.f + __expf(-(p + dogenB[0])));
  }
}

__global__ void final_kernel(float* __restrict__ prob, const float* __restrict__ mixb,
                             const float* __restrict__ rowsum, const int* __restrict__ enc_in) {
  int row = blockIdx.y;
  int v = blockIdx.x * 256 + threadIdx.x;
  float mx = mixb[row], rs = rowsum[row];
  size_t idx = (size_t)row * VDIM + v;
  float val = prob[idx] * (mx / rs);
  if (v == enc_in[row]) val += 1.f - mx;
  prob[idx] = val;
}

// ---------------- host ----------------
extern "C" void kernel_launch(void* const* d_in, const int* in_sizes, int n_in, void* d_out,
                              int out_size, void* d_ws, size_t ws_size, hipStream_t stream) {
  const int* input_ = (const int*)d_in[0];
  const int* enc_in = (const int*)d_in[1];
  const float* enc_h = (const float*)d_in[2];
  const float* enc_out = (const float*)d_in[3];
  const float* emb = (const float*)d_in[4];
  const float* attn_W = (const float*)d_in[5];
  const float* attn_b = (const float*)d_in[6];
  const float* comb_W = (const float*)d_in[7];
  const float* comb_b = (const float*)d_in[8];
  const float* Wih = (const float*)d_in[9];
  const float* Whh = (const float*)d_in[10];
  const float* bih = (const float*)d_in[11];
  const float* bhh = (const float*)d_in[12];
  const float* out_W = (const float*)d_in[13];
  const float* out_b = (const float*)d_in[14];
  const float* dogen_W = (const float*)d_in[15];
  const float* dogen_b = (const float*)d_in[16];
  const float* copy_W = (const float*)d_in[17];
  const float* copy_b = (const float*)d_in[18];

  float* prob = (float*)d_out;
  float* attn_out = prob + (size_t)MROWS * VDIM;

  char* ws = (char*)d_ws;
  size_t off = 0;
  auto alloc = [&](size_t bytes) {
    off = (off + 255) & ~(size_t)255;
    void* p = ws + off;
    off += bytes;
    return p;
  };
  unsigned short* outW_bf = (unsigned short*)alloc((size_t)VDIM * HDIM * 2);
  unsigned short* combW_bf = (unsigned short*)alloc((size_t)HDIM * H2 * 2);
  unsigned short* Wih_bf = (unsigned short*)alloc((size_t)H3 * HDIM * 2);
  unsigned short* A4 = (unsigned short*)alloc((size_t)MROWS * H2 * 2);
  unsigned short* xbf = (unsigned short*)alloc((size_t)MROWS * HDIM * 2);
  unsigned short* Ab = (unsigned short*)alloc((size_t)MROWS * HDIM * 2);
  float* emb_f = (float*)alloc((size_t)MROWS * HDIM * 4);
  float* gi = (float*)alloc((size_t)MROWS * H3 * 4);
  float* outF = (float*)alloc((size_t)MROWS * HDIM * 4);
  unsigned short* hbufbf = (unsigned short*)alloc((size_t)129 * HSTEP * 2);
  int* flags = (int*)alloc(129 * GRU_WGS * 4);
  float* rowsum = (float*)alloc(4096);
  float* epart = (float*)alloc(4096);
  float* dpart = (float*)alloc(4096);
  float* alphas = (float*)alloc((size_t)MROWS * LDIM * 4);
  float* ctx = (float*)alloc((size_t)MROWS * HDIM * 4);
  float* mixb = (float*)alloc(4096);

  // prep: converts + init
  cvt_kernel<<<(VDIM * HDIM / 4 + 255) / 256, 256, 0, stream>>>(out_W, outW_bf, VDIM * HDIM / 4);
  cvt_kernel<<<(HDIM * H2 / 4 + 255) / 256, 256, 0, stream>>>(comb_W, combW_bf, HDIM * H2 / 4);
  cvt_kernel<<<(H3 * HDIM / 4 + 255) / 256, 256, 0, stream>>>(Wih, Wih_bf, H3 * HDIM / 4);
  init_kernel<<<1, 256, 0, stream>>>(enc_h, hbufbf, rowsum, flags);
  embed_kernel<<<MROWS, 256, 0, stream>>>(input_, emb, emb_f, A4);
  // attention path (fp32)
  attn_kernel<<<dim3(LDIM, BDIM), 128, 0, stream>>>(emb_f, enc_h, attn_W, attn_b, attn_out);
  einsum_kernel<<<dim3(LDIM, BDIM), 256, 0, stream>>>(attn_out, enc_out, nullptr, A4, 0);
  // comb GEMM -> x (bf16), gi GEMM
  gemm_bt<<<dim3(4, 8), 256, 0, stream>>>(A4, combW_bf, HDIM, H2, comb_b, 0, nullptr, xbf, nullptr);
  gemm_bt<<<dim3(12, 8), 256, 0, stream>>>(xbf, Wih_bf, H3, HDIM, bih, 1, gi, nullptr, nullptr);
  // sequential GRU
  gru_kernel<<<GRU_WGS, 64, 0, stream>>>(Whh, bhh, gi, enc_h, hbufbf, outF, Ab, flags);
  // big output GEMM: explogits into prob region + row sums
  gemm_bt<<<dim3(VDIM / 128, 8), 256, 0, stream>>>(Ab, outW_bf, VDIM, HDIM, out_b, 2, prob, nullptr, rowsum);
  // copy path
  dots_kernel<<<32, 256, 0, stream>>>(enc_out, outF, copy_W, epart, dpart);
  alphas_kernel<<<dim3(LDIM, BDIM), 128, 0, stream>>>(dpart, epart, enc_in, copy_b, alphas);
  einsum_kernel<<<dim3(LDIM, BDIM), 256, 0, stream>>>(alphas, enc_out, ctx, nullptr, 1);
  mix_kernel<<<16, 256, 0, stream>>>(outF, ctx, emb_f, dogen_W, dogen_b, mixb);
  // final blend (in-place on prob region)
  final_kernel<<<dim3(VDIM / 256, MROWS), 256, 0, stream>>>(prob, mixb, rowsum, enc_in);
}